// Round 6
// baseline (76.577 us; speedup 1.0000x reference)
//
#include <hip/hip_runtime.h>

// RetinaNet target encoder for MI355X — round 6: round-5 LDS-tile structure
// + exact zero-IoU skipping via wave-bbox test on the scalar pipe.
// Inputs: bboxes [N,4] f32 xyxy, labels [N] i32, priors [M,4] f32 cxcywh.
// Outputs (concat): reg_targets [M,4] f32, cls_targets [M] (written as f32).
//
// Skip is EXACT: non-overlap => clamped w or h == 0 => inter == 0 =>
// iou = 0/(area_a+area_b) == 0.0f bit-exactly in the reference too.
// Skip test uses a monotone float->uint key (b ^ ((b>>31)|0x80000000)) so
// uniform integer compares run on the scalar pipe; key order == float order
// (±0 collapse only makes the test conservative). Skip => gx1>=wave_x2 etc.
// => all 64 lane IoUs for this GT are exactly 0.

static constexpr float NEG_THRESH = 0.4f;
static constexpr float POS_THRESH = 0.5f;
static constexpr int N_GT = 1024;
static constexpr int GT_CHUNK = 32;
static constexpr int NCHUNK = N_GT / GT_CHUNK;   // 32
static constexpr int MPAD = 49152;               // M rounded up to 256
static constexpr int BLK = 256;                  // priors per block
static constexpr int NB = MPAD / BLK;            // 192 prior blocks
static constexpr int STRIDE = 264;               // 264 % 32 == 8 -> <=2-way banks

__device__ __forceinline__ float iou_ab(float ax1, float ay1, float ax2, float ay2,
                                        float area_a,
                                        float bx1, float by1, float bx2, float by2,
                                        float area_b) {
#pragma clang fp contract(off)
    float ltx = fmaxf(ax1, bx1);
    float lty = fmaxf(ay1, by1);
    float rbx = fminf(ax2, bx2);
    float rby = fminf(ay2, by2);
    float w = rbx - ltx; if (w < 0.0f) w = 0.0f;
    float h = rby - lty; if (h < 0.0f) h = 0.0f;
    float inter = w * h;
    return inter / (area_a + area_b - inter);
}

// Monotone float -> uint key: k(a) < k(b) <=> a < b (no NaNs here; ±0 collapse
// is conservative for the skip test).
__device__ __forceinline__ unsigned fkey(float f) {
    int b = __float_as_int(f);
    return (unsigned)(b ^ ((b >> 31) | 0x80000000));
}

__device__ __forceinline__ float rfl(float v) {
    return __uint_as_float((unsigned)__builtin_amdgcn_readfirstlane(__float_as_int(v)));
}

// ---------------- Fused kernel ----------------
__global__ void __launch_bounds__(256) fused_kernel(
        const float* __restrict__ bboxes,
        const float* __restrict__ priors,
        float* __restrict__ part1iou,             // [NCHUNK][MPAD]
        unsigned short* __restrict__ part1idx,    // [NCHUNK][MPAD]
        unsigned long long* __restrict__ partD,   // [NB][N_GT]
        int* __restrict__ force_n,                // [M], init -1 (chunk 0)
        int M) {
#pragma clang fp contract(off)
    __shared__ float tile[GT_CHUNK][STRIDE];

    int tid = threadIdx.x;
    int bx = blockIdx.x;
    int n0 = blockIdx.y * GT_CHUNK;
    int m = bx * BLK + tid;
    bool valid = (m < M);

    float4 p = valid ? reinterpret_cast<const float4*>(priors)[m]
                     : make_float4(0.f, 0.f, 0.f, 0.f);
    float bx1 = p.x - p.z / 2.0f;
    float by1 = p.y - p.w / 2.0f;
    float bx2 = p.x + p.z / 2.0f;
    float by2 = p.y + p.w / 2.0f;
    float area_b = (bx2 - bx1) * (by2 - by1);

    // Wave bounding box over its 64 priors (invalid lanes neutral).
    float mnx = valid ? bx1 : 1e30f;
    float mny = valid ? by1 : 1e30f;
    float mxx = valid ? bx2 : -1e30f;
    float mxy = valid ? by2 : -1e30f;
#pragma unroll
    for (int mk = 1; mk < 64; mk <<= 1) {
        mnx = fminf(mnx, __shfl_xor(mnx, mk));
        mny = fminf(mny, __shfl_xor(mny, mk));
        mxx = fmaxf(mxx, __shfl_xor(mxx, mk));
        mxy = fmaxf(mxy, __shfl_xor(mxy, mk));
    }
    // Wave-uniform integer keys (SGPRs).
    unsigned kwx1 = fkey(rfl(mnx));
    unsigned kwy1 = fkey(rfl(mny));
    unsigned kwx2 = fkey(rfl(mxx));
    unsigned kwy2 = fkey(rfl(mxy));

    float best = 0.0f;   // iou >= 0 always; all-zero row -> argmax = 0 (numpy)
    int bestj = 0;

    for (int j = 0; j < GT_CHUNK; ++j) {
        // GT box: uniform index -> scalar load; key math is scalar int ops.
        float4 g = reinterpret_cast<const float4*>(bboxes)[n0 + j];
        bool ovl = (fkey(g.x) < kwx2) & (fkey(g.z) > kwx1) &
                   (fkey(g.y) < kwy2) & (fkey(g.w) > kwy1);
        if (ovl) {
            float ga = (g.z - g.x) * (g.w - g.y);
            float iou = iou_ab(g.x, g.y, g.z, g.w, ga,
                               bx1, by1, bx2, by2, area_b);
            // per-prior argmax: strict > ascending j == numpy first-max
            if (iou > best) { best = iou; bestj = j; }
            tile[j][tid] = valid ? iou : -1.0f;
        } else {
            // all 64 IoUs for this GT are exactly 0 in the reference.
            tile[j][tid] = -1.0f;
        }
    }

    if (valid) {
        size_t row = (size_t)blockIdx.y * MPAD + m;
        part1iou[row] = best;
        part1idx[row] = (unsigned short)(n0 + bestj);
        if (blockIdx.y == 0) force_n[m] = -1;   // replay-safe init for rs
    }

    __syncthreads();

    // phase 2: per-GT argmax over this block's 256 priors (8 lanes per GT).
    int j = tid >> 3;
    int sub = tid & 7;
    int m0 = bx * BLK;

    float bi = -2.0f;
    int bm = 0;
    int i = sub;
#pragma unroll 8
    for (int k = 0; k < BLK / 8; ++k) {
        float v = tile[j][i];
        if (v > bi) { bi = v; bm = i; }    // ascending i: smallest i on ties
        i += 8;
    }
    // group max, then smallest m among maxima (exact numpy tie-break)
    float gm = bi;
    gm = fmaxf(gm, __shfl_xor(gm, 1));
    gm = fmaxf(gm, __shfl_xor(gm, 2));
    gm = fmaxf(gm, __shfl_xor(gm, 4));
    int cand = (bi == gm) ? (m0 + bm) : 0x7FFFFFFF;
    cand = min(cand, __shfl_xor(cand, 1));
    cand = min(cand, __shfl_xor(cand, 2));
    cand = min(cand, __shfl_xor(cand, 4));
    if (sub == 0) {
        // gm <= 0 rows can never win the global per-GT argmax (every GT has a
        // positive-IoU prior); write 0 so -1 sentinels can't poison the reduce.
        unsigned long long packed = (gm <= 0.0f) ? 0ULL :
            (((unsigned long long)__float_as_uint(gm) << 32) |
             (unsigned long long)(0xFFFFFFFFu - (unsigned)cand));
        partD[(size_t)bx * N_GT + n0 + j] = packed;
    }
}

// ---------------- RS: per-GT winner -> forced-assignment scatter -------------
__global__ void rs_kernel(const unsigned long long* __restrict__ partD,
                          int* __restrict__ force_n) {
    int n = blockIdx.x * blockDim.x + threadIdx.x;
    if (n >= N_GT) return;
    unsigned long long best = 0ULL;
    for (int c = 0; c < NB; ++c) {              // coalesced: lanes read adjacent n
        unsigned long long v = partD[(size_t)c * N_GT + n];
        if (v > best) best = v;
    }
    int m = (int)(0xFFFFFFFFu - (unsigned)(best & 0xFFFFFFFFull));
    atomicMax(&force_n[m], n);   // duplicate priors: last write in np == max n
}

// ---------------- E: reduce per-prior partials + encode ----------------------
__global__ void __launch_bounds__(256) encode_kernel(
        const float* __restrict__ bboxes,
        const int* __restrict__ labels,
        const float* __restrict__ priors,
        const float* __restrict__ part1iou,
        const unsigned short* __restrict__ part1idx,
        const int* __restrict__ force_n,
        float* __restrict__ out, int M) {
#pragma clang fp contract(off)
    int m = blockIdx.x * 256 + threadIdx.x;
    if (m >= M) return;

    float bi = part1iou[m];
    int bn = part1idx[m];
    for (int c = 1; c < NCHUNK; ++c) {
        float v = part1iou[(size_t)c * MPAD + m];
        if (v > bi) { bi = v; bn = part1idx[(size_t)c * MPAD + m]; }
    }   // strict > ascending c == smallest n on ties (numpy first-max)

    float iou = bi;
    int mid = bn;
    int f = force_n[m];
    if (f >= 0) { mid = f; iou = POS_THRESH; }

    float4 g = reinterpret_cast<const float4*>(bboxes)[mid];
    float mcx = (g.x + g.z) / 2.0f;
    float mcy = (g.y + g.w) / 2.0f;
    float mw = g.z - g.x;
    float mh = g.w - g.y;

    float4 p = reinterpret_cast<const float4*>(priors)[m];
    float dcx = ((mcx - p.x) / p.z) / 0.1f;
    float dcy = ((mcy - p.y) / p.w) / 0.1f;
    float dw = logf(mw / p.z) / 0.2f;
    float dh = logf(mh / p.w) / 0.2f;

    reinterpret_cast<float4*>(out)[m] = make_float4(dcx, dcy, dw, dh);

    int cls = labels[mid];
    if (iou < POS_THRESH) cls = -1;
    if (iou < NEG_THRESH) cls = 0;
    out[(size_t)4 * M + m] = (float)cls;
}

extern "C" void kernel_launch(void* const* d_in, const int* in_sizes, int n_in,
                              void* d_out, int out_size, void* d_ws, size_t ws_size,
                              hipStream_t stream) {
    const float* bboxes = (const float*)d_in[0];
    const int* labels = (const int*)d_in[1];
    const float* priors = (const float*)d_in[2];
    int M = in_sizes[2] / 4;
    float* out = (float*)d_out;

    char* ws = (char*)d_ws;
    float* part1iou = (float*)ws;                                                   // 6.29 MB
    unsigned short* part1idx = (unsigned short*)(ws + (size_t)NCHUNK * MPAD * 4);   // 3.15 MB
    unsigned long long* partD = (unsigned long long*)(ws + (size_t)NCHUNK * MPAD * 6);  // 1.57 MB
    int* force_n = (int*)(ws + (size_t)NCHUNK * MPAD * 6 + (size_t)NB * N_GT * 8);

    fused_kernel<<<dim3(NB, NCHUNK), 256, 0, stream>>>(bboxes, priors, part1iou,
                                                       part1idx, partD, force_n, M);
    rs_kernel<<<(N_GT + 255) / 256, 256, 0, stream>>>(partD, force_n);
    encode_kernel<<<(MPAD + 255) / 256, 256, 0, stream>>>(bboxes, labels, priors,
                                                          part1iou, part1idx,
                                                          force_n, out, M);
}

// Round 7
// 62.764 us; speedup vs baseline: 1.2201x; 1.2201x over previous
//
#include <hip/hip_runtime.h>

// RetinaNet target encoder for MI355X — round 7: block-level GT compaction.
// Inputs: bboxes [N,4] f32 xyxy, labels [N] i32, priors [M,4] f32 cxcywh.
// Outputs (concat): reg_targets [M,4] f32, cls_targets [M] (written as f32).
//
// N = 1024, M = 49104. Grid (192, 16): block = 256 priors x 64 GTs.
//  - block bbox over its 256 priors (shfl+LDS reduce, once)
//  - wave 0 tests the 64 GTs against the block bbox; failing GTs have ALL
//    pair-IoUs exactly 0.0 in the reference (min(gx2,px2)-max(gx1,px1) <= 0
//    etc., since px ranges lie inside the block bbox) -> skipping is exact.
//  - ballot+popcount order-preserving compaction into slist (ascending j),
//    padded to a multiple of 16 with slist[0] (harmless: duplicate rows give
//    identical phase-2 writes; strict-> argmax ignores repeated equal vals).
//  - per 16-row batch: phase 1 IoU -> regs (per-prior argmax) + LDS tile;
//    phase 2 re-reads tile transposed (16 lanes/GT) -> partD[bx][gt].
//  - partD pre-zeroed (memset); zero rows can't win: every GT overlaps some
//    level-7 prior with IoU > 0.
// Tie semantics == numpy everywhere: strict > over ascending index for both
// argmaxes; packed u64 (iou_bits<<32)|(~m) max == (max iou, smallest m);
// force-assign duplicates: atomicMax(n) == numpy last-write-wins.

static constexpr float NEG_THRESH = 0.4f;
static constexpr float POS_THRESH = 0.5f;
static constexpr int N_GT = 1024;
static constexpr int GT_PER_BLK = 64;
static constexpr int NCHUNK = N_GT / GT_PER_BLK;   // 16
static constexpr int MPAD = 49152;                 // M rounded up to 256
static constexpr int BLK = 256;                    // priors per block
static constexpr int NB = MPAD / BLK;              // 192 prior blocks
static constexpr int BATCH = 16;                   // tile rows per batch
static constexpr int STRIDE = 264;                 // <=2-way LDS banks (free)

__device__ __forceinline__ float iou_ab(float ax1, float ay1, float ax2, float ay2,
                                        float area_a,
                                        float bx1, float by1, float bx2, float by2,
                                        float area_b) {
#pragma clang fp contract(off)
    float ltx = fmaxf(ax1, bx1);
    float lty = fmaxf(ay1, by1);
    float rbx = fminf(ax2, bx2);
    float rby = fminf(ay2, by2);
    float w = rbx - ltx; if (w < 0.0f) w = 0.0f;
    float h = rby - lty; if (h < 0.0f) h = 0.0f;
    float inter = w * h;
    return inter / (area_a + area_b - inter);
}

// ---------------- Fused kernel ----------------
__global__ void __launch_bounds__(256) fused_kernel(
        const float* __restrict__ bboxes,
        const float* __restrict__ priors,
        float* __restrict__ part1iou,             // [NCHUNK][MPAD]
        unsigned short* __restrict__ part1idx,    // [NCHUNK][MPAD]
        unsigned long long* __restrict__ partD,   // [NB][N_GT], pre-zeroed
        int* __restrict__ force_n,                // [M], init -1 (chunk 0)
        int M) {
#pragma clang fp contract(off)
    __shared__ float tile[BATCH][STRIDE];          // 16.9 KB
    __shared__ unsigned short slist[GT_PER_BLK];
    __shared__ int scount;
    __shared__ float sbb[4][4];                    // per-wave partial bbox

    int tid = threadIdx.x;
    int lane = tid & 63;
    int wid = tid >> 6;
    int bx = blockIdx.x;
    int n0 = blockIdx.y * GT_PER_BLK;
    int m = bx * BLK + tid;
    bool valid = (m < M);

    float4 p = valid ? reinterpret_cast<const float4*>(priors)[m]
                     : make_float4(0.f, 0.f, 0.f, 0.f);
    float bx1 = p.x - p.z / 2.0f;
    float by1 = p.y - p.w / 2.0f;
    float bx2 = p.x + p.z / 2.0f;
    float by2 = p.y + p.w / 2.0f;
    float area_b = (bx2 - bx1) * (by2 - by1);

    // ---- block bbox over 256 priors ----
    float mnx = valid ? bx1 : 1e30f;
    float mny = valid ? by1 : 1e30f;
    float mxx = valid ? bx2 : -1e30f;
    float mxy = valid ? by2 : -1e30f;
#pragma unroll
    for (int mk = 1; mk < 64; mk <<= 1) {
        mnx = fminf(mnx, __shfl_xor(mnx, mk));
        mny = fminf(mny, __shfl_xor(mny, mk));
        mxx = fmaxf(mxx, __shfl_xor(mxx, mk));
        mxy = fmaxf(mxy, __shfl_xor(mxy, mk));
    }
    if (lane == 0) {
        sbb[wid][0] = mnx; sbb[wid][1] = mny; sbb[wid][2] = mxx; sbb[wid][3] = mxy;
    }
    __syncthreads();
    float BX1 = fminf(fminf(sbb[0][0], sbb[1][0]), fminf(sbb[2][0], sbb[3][0]));
    float BY1 = fminf(fminf(sbb[0][1], sbb[1][1]), fminf(sbb[2][1], sbb[3][1]));
    float BX2 = fmaxf(fmaxf(sbb[0][2], sbb[1][2]), fmaxf(sbb[2][2], sbb[3][2]));
    float BY2 = fmaxf(fmaxf(sbb[0][3], sbb[1][3]), fmaxf(sbb[2][3], sbb[3][3]));

    // ---- wave 0: test 64 GTs, order-preserving compaction ----
    if (tid < 64) {
        float4 g = reinterpret_cast<const float4*>(bboxes)[n0 + tid];
        bool hit = (g.x < BX2) & (g.z > BX1) & (g.y < BY2) & (g.w > BY1);
        unsigned long long bal = __ballot(hit);
        int cnt = __popcll(bal);
        if (hit) {
            int pos = __popcll(bal & ((1ull << tid) - 1ull));
            slist[pos] = (unsigned short)tid;
        }
        if (tid == 0) scount = cnt;
        // pad to multiple of BATCH with slist[0] (only if cnt > 0)
        if (tid >= cnt && tid < ((cnt + BATCH - 1) / BATCH) * BATCH && cnt > 0) {
            // slist[0] not yet visible to other lanes? same wave: ballot'ed
            // lanes wrote above; need cross-lane visibility -> do after sync.
        }
    }
    __syncthreads();
    int count = scount;
    int padded = ((count + BATCH - 1) / BATCH) * BATCH;
    if (tid >= count && tid < padded) slist[tid] = slist[0];  // count>0 here
    __syncthreads();

    float best = 0.0f;            // iou >= 0; all-zero row -> argmax 0 (numpy)
    int bestjr = n0;              // global GT index of per-prior argmax

    int m0 = bx * BLK;
    int jrow = tid >> 4;          // phase-2: 16 lanes per row
    int sub = tid & 15;

    for (int b = 0; b < padded; b += BATCH) {
        // ---- phase 1: 16 active GT rows, straight-line ----
#pragma unroll
        for (int r = 0; r < BATCH; ++r) {
            int jl = __builtin_amdgcn_readfirstlane((int)slist[b + r]);
            float4 g = reinterpret_cast<const float4*>(bboxes)[n0 + jl];
            float ga = (g.z - g.x) * (g.w - g.y);
            float iou = iou_ab(g.x, g.y, g.z, g.w, ga,
                               bx1, by1, bx2, by2, area_b);
            // strict > over ascending real j (slist ascending; padded dups
            // are equal values of an earlier j -> never displace)
            if (iou > best) { best = iou; bestjr = n0 + jl; }
            tile[r][tid] = valid ? iou : -1.0f;
        }
        __syncthreads();

        // ---- phase 2: per-GT argmax over this block's 256 priors ----
        float bi = -2.0f;
        int bm = 0;
        int i = sub;
#pragma unroll
        for (int k = 0; k < BLK / 16; ++k) {
            float v = tile[jrow][i];
            if (v > bi) { bi = v; bm = i; }   // ascending i: smallest on tie
            i += 16;
        }
        float gm = bi;
        gm = fmaxf(gm, __shfl_xor(gm, 1));
        gm = fmaxf(gm, __shfl_xor(gm, 2));
        gm = fmaxf(gm, __shfl_xor(gm, 4));
        gm = fmaxf(gm, __shfl_xor(gm, 8));
        int cand = (bi == gm) ? (m0 + bm) : 0x7FFFFFFF;
        cand = min(cand, __shfl_xor(cand, 1));
        cand = min(cand, __shfl_xor(cand, 2));
        cand = min(cand, __shfl_xor(cand, 4));
        cand = min(cand, __shfl_xor(cand, 8));
        if (sub == 0 && gm > 0.0f) {
            int jr2 = (int)slist[b + jrow];   // duplicate rows: identical value
            partD[(size_t)bx * N_GT + n0 + jr2] =
                ((unsigned long long)__float_as_uint(gm) << 32) |
                (unsigned long long)(0xFFFFFFFFu - (unsigned)cand);
        }
        __syncthreads();   // protect tile before next batch overwrites
    }

    if (valid) {
        size_t row = (size_t)blockIdx.y * MPAD + m;
        part1iou[row] = best;
        part1idx[row] = (unsigned short)bestjr;
        if (blockIdx.y == 0) force_n[m] = -1;   // replay-safe init for rs
    }
}

// ---------------- RS: per-GT winner -> forced-assignment scatter -------------
__global__ void rs_kernel(const unsigned long long* __restrict__ partD,
                          int* __restrict__ force_n) {
    int n = blockIdx.x * blockDim.x + threadIdx.x;
    if (n >= N_GT) return;
    unsigned long long best = 0ULL;
    for (int c = 0; c < NB; ++c) {
        unsigned long long v = partD[(size_t)c * N_GT + n];
        if (v > best) best = v;
    }
    int m = (int)(0xFFFFFFFFu - (unsigned)(best & 0xFFFFFFFFull));
    atomicMax(&force_n[m], n);   // duplicate priors: last write in np == max n
}

// ---------------- E: reduce per-prior partials + encode ----------------------
__global__ void __launch_bounds__(256) encode_kernel(
        const float* __restrict__ bboxes,
        const int* __restrict__ labels,
        const float* __restrict__ priors,
        const float* __restrict__ part1iou,
        const unsigned short* __restrict__ part1idx,
        const int* __restrict__ force_n,
        float* __restrict__ out, int M) {
#pragma clang fp contract(off)
    int m = blockIdx.x * 256 + threadIdx.x;
    if (m >= M) return;

    float bi = part1iou[m];
    int bn = part1idx[m];
    for (int c = 1; c < NCHUNK; ++c) {
        float v = part1iou[(size_t)c * MPAD + m];
        if (v > bi) { bi = v; bn = part1idx[(size_t)c * MPAD + m]; }
    }   // strict > ascending c == smallest n on ties (numpy first-max)

    float iou = bi;
    int mid = bn;
    int f = force_n[m];
    if (f >= 0) { mid = f; iou = POS_THRESH; }

    float4 g = reinterpret_cast<const float4*>(bboxes)[mid];
    float mcx = (g.x + g.z) / 2.0f;
    float mcy = (g.y + g.w) / 2.0f;
    float mw = g.z - g.x;
    float mh = g.w - g.y;

    float4 p = reinterpret_cast<const float4*>(priors)[m];
    float dcx = ((mcx - p.x) / p.z) / 0.1f;
    float dcy = ((mcy - p.y) / p.w) / 0.1f;
    float dw = logf(mw / p.z) / 0.2f;
    float dh = logf(mh / p.w) / 0.2f;

    reinterpret_cast<float4*>(out)[m] = make_float4(dcx, dcy, dw, dh);

    int cls = labels[mid];
    if (iou < POS_THRESH) cls = -1;
    if (iou < NEG_THRESH) cls = 0;
    out[(size_t)4 * M + m] = (float)cls;
}

extern "C" void kernel_launch(void* const* d_in, const int* in_sizes, int n_in,
                              void* d_out, int out_size, void* d_ws, size_t ws_size,
                              hipStream_t stream) {
    const float* bboxes = (const float*)d_in[0];
    const int* labels = (const int*)d_in[1];
    const float* priors = (const float*)d_in[2];
    int M = in_sizes[2] / 4;
    float* out = (float*)d_out;

    // Workspace layout (~6.5 MB):
    char* ws = (char*)d_ws;
    float* part1iou = (float*)ws;                                   // 16*MPAD*4 = 3.15 MB
    unsigned short* part1idx =
        (unsigned short*)(ws + (size_t)NCHUNK * MPAD * 4);          // 1.57 MB
    unsigned long long* partD =
        (unsigned long long*)(ws + (size_t)NCHUNK * MPAD * 6);      // 1.57 MB
    int* force_n =
        (int*)(ws + (size_t)NCHUNK * MPAD * 6 + (size_t)NB * N_GT * 8);

    // partD must be 0 each call (compaction skips inactive entries; replay-safe)
    hipMemsetAsync(partD, 0, (size_t)NB * N_GT * 8, stream);

    fused_kernel<<<dim3(NB, NCHUNK), 256, 0, stream>>>(bboxes, priors, part1iou,
                                                       part1idx, partD, force_n, M);
    rs_kernel<<<(N_GT + 255) / 256, 256, 0, stream>>>(partD, force_n);
    encode_kernel<<<(MPAD + 255) / 256, 256, 0, stream>>>(bboxes, labels, priors,
                                                          part1iou, part1idx,
                                                          force_n, out, M);
}